// Round 1
// baseline (1755.493 us; speedup 1.0000x reference)
//
#include <hip/hip_runtime.h>
#include <hip/hip_bf16.h>

// Problem constants (fixed by setup_inputs)
constexpr int NROWS = 100000;
constexpr int K     = 512;
constexpr int C     = 64;
constexpr int E     = 3200000;

// ---------------------------------------------------------------------------
// GEMM: h[N,64] = x[N,512] @ w[512,64], fp32 vector ALU.
// Tile 64 rows x 64 cols, KC=64, 4x4 register blocking per thread.
// ---------------------------------------------------------------------------
__global__ __launch_bounds__(256) void gemm64(const float* __restrict__ x,
                                              const float* __restrict__ w,
                                              float* __restrict__ h) {
  __shared__ float xs[64][65];   // +1 pad: xs[r][kk] broadcast groups hit distinct banks
  __shared__ float ws[64][64];
  const int t   = threadIdx.x;
  const int cg  = (t & 15) * 4;   // col base: 0..60
  const int rg  = (t >> 4) * 4;   // row base: 0..60
  const int row0 = blockIdx.x * 64;

  float acc[4][4] = {};

  for (int k0 = 0; k0 < K; k0 += 64) {
    // stage W chunk [64k x 64c] = 1024 float4, 4 per thread
    {
      const float4* wg  = (const float4*)(w + (size_t)k0 * C);
      float4*       wsv = (float4*)&ws[0][0];
#pragma unroll
      for (int i = 0; i < 4; ++i) wsv[t + 256 * i] = wg[t + 256 * i];
    }
    // stage x chunk [64r x 64k]
    {
#pragma unroll
      for (int i = 0; i < 4; ++i) {
        int idx = t + 256 * i;        // 0..1023
        int r   = idx >> 4;           // 0..63
        int kk  = (idx & 15) * 4;     // 0..60
        int gr  = row0 + r;
        if (gr >= NROWS) gr = NROWS - 1;   // clamp: avoid OOB read, result discarded
        float4 v = *(const float4*)(x + (size_t)gr * K + k0 + kk);
        xs[r][kk]     = v.x;
        xs[r][kk + 1] = v.y;
        xs[r][kk + 2] = v.z;
        xs[r][kk + 3] = v.w;
      }
    }
    __syncthreads();

#pragma unroll
    for (int kk = 0; kk < 64; ++kk) {
      float4 wv = *(const float4*)&ws[kk][cg];
      float xr[4];
#pragma unroll
      for (int i = 0; i < 4; ++i) xr[i] = xs[rg + i][kk];
#pragma unroll
      for (int i = 0; i < 4; ++i) {
        acc[i][0] += xr[i] * wv.x;
        acc[i][1] += xr[i] * wv.y;
        acc[i][2] += xr[i] * wv.z;
        acc[i][3] += xr[i] * wv.w;
      }
    }
    __syncthreads();
  }

#pragma unroll
  for (int i = 0; i < 4; ++i) {
    int gr = row0 + rg + i;
    if (gr < NROWS) {
      float4 v = {acc[i][0], acc[i][1], acc[i][2], acc[i][3]};
      *(float4*)(h + (size_t)gr * C + cg) = v;
    }
  }
}

// ---------------------------------------------------------------------------
// SPMM (push / atomic): hout[row[e]] += val[e] * hin[col[e]], one wave per edge,
// lane = column. hout must be zeroed beforehand.
// ---------------------------------------------------------------------------
__global__ __launch_bounds__(256) void spmm_atomic(const int* __restrict__ row,
                                                   const int* __restrict__ col,
                                                   const float* __restrict__ val,
                                                   const float* __restrict__ hin,
                                                   float* hout) {
  int e = blockIdx.x * 4 + (threadIdx.x >> 6);
  if (e >= E) return;
  int   c  = threadIdx.x & 63;
  int   r  = row[e];
  int   cl = col[e];
  float v  = val[e];
  atomicAdd(&hout[(size_t)r * C + c], v * hin[(size_t)cl * C + c]);
}

// ---------------------------------------------------------------------------
// bias + log_softmax, one wave per row (C=64 = wave width)
// ---------------------------------------------------------------------------
__global__ __launch_bounds__(256) void bias_lsm(const float* __restrict__ h,
                                                const float* __restrict__ bias,
                                                float* __restrict__ out) {
  int r = blockIdx.x * 4 + (threadIdx.x >> 6);
  if (r >= NROWS) return;
  int   c = threadIdx.x & 63;
  float v = h[(size_t)r * C + c] + bias[c];

  float m = v;
#pragma unroll
  for (int off = 32; off; off >>= 1) m = fmaxf(m, __shfl_xor(m, off, 64));
  float ex = __expf(v - m);
  float s  = ex;
#pragma unroll
  for (int off = 32; off; off >>= 1) s += __shfl_xor(s, off, 64);

  out[(size_t)r * C + c] = v - m - __logf(s);
}

// ---------------------------------------------------------------------------
extern "C" void kernel_launch(void* const* d_in, const int* in_sizes, int n_in,
                              void* d_out, int out_size, void* d_ws, size_t ws_size,
                              hipStream_t stream) {
  const float* x    = (const float*)d_in[0];
  const float* w    = (const float*)d_in[1];
  const float* bias = (const float*)d_in[2];
  const int*   erow = (const int*)d_in[3];
  const int*   ecol = (const int*)d_in[4];
  const float* eval = (const float*)d_in[5];
  // d_in[6] = nlayers (always 2 per setup_inputs; hard-coded below)

  float* out = (float*)d_out;
  float* h0  = (float*)d_ws;
  float* h1  = h0 + (size_t)NROWS * C;
  const size_t hbytes = (size_t)NROWS * C * sizeof(float);

  // h0 = x @ w
  gemm64<<<(NROWS + 63) / 64, 256, 0, stream>>>(x, w, h0);

  // layer 1: h1 = A @ h0
  hipMemsetAsync(h1, 0, hbytes, stream);
  spmm_atomic<<<(E + 3) / 4, 256, 0, stream>>>(erow, ecol, eval, h0, h1);

  // layer 2: h0 = A @ h1
  hipMemsetAsync(h0, 0, hbytes, stream);
  spmm_atomic<<<(E + 3) / 4, 256, 0, stream>>>(erow, ecol, eval, h1, h0);

  // out = log_softmax(h0 + bias)
  bias_lsm<<<(NROWS + 3) / 4, 256, 0, stream>>>(h0, bias, out);
}

// Round 2
// 958.470 us; speedup vs baseline: 1.8316x; 1.8316x over previous
//
#include <hip/hip_runtime.h>
#include <hip/hip_bf16.h>

// Problem constants (fixed by setup_inputs)
constexpr int NROWS = 100000;
constexpr int K     = 512;
constexpr int C     = 64;
constexpr int E     = 3200000;

// ---------------------------------------------------------------------------
// GEMM: h[N,64] = x[N,512] @ w[512,64], fp32 vector ALU.
// Tile 64 rows x 64 cols, KC=64, 4x4 register blocking per thread.
// ---------------------------------------------------------------------------
__global__ __launch_bounds__(256) void gemm64(const float* __restrict__ x,
                                              const float* __restrict__ w,
                                              float* __restrict__ h) {
  __shared__ float xs[64][65];
  __shared__ float ws[64][64];
  const int t   = threadIdx.x;
  const int cg  = (t & 15) * 4;   // col base: 0..60
  const int rg  = (t >> 4) * 4;   // row base: 0..60
  const int row0 = blockIdx.x * 64;

  float acc[4][4] = {};

  for (int k0 = 0; k0 < K; k0 += 64) {
    {
      const float4* wg  = (const float4*)(w + (size_t)k0 * C);
      float4*       wsv = (float4*)&ws[0][0];
#pragma unroll
      for (int i = 0; i < 4; ++i) wsv[t + 256 * i] = wg[t + 256 * i];
    }
    {
#pragma unroll
      for (int i = 0; i < 4; ++i) {
        int idx = t + 256 * i;
        int r   = idx >> 4;
        int kk  = (idx & 15) * 4;
        int gr  = row0 + r;
        if (gr >= NROWS) gr = NROWS - 1;
        float4 v = *(const float4*)(x + (size_t)gr * K + k0 + kk);
        xs[r][kk]     = v.x;
        xs[r][kk + 1] = v.y;
        xs[r][kk + 2] = v.z;
        xs[r][kk + 3] = v.w;
      }
    }
    __syncthreads();

#pragma unroll
    for (int kk = 0; kk < 64; ++kk) {
      float4 wv = *(const float4*)&ws[kk][cg];
      float xr[4];
#pragma unroll
      for (int i = 0; i < 4; ++i) xr[i] = xs[rg + i][kk];
#pragma unroll
      for (int i = 0; i < 4; ++i) {
        acc[i][0] += xr[i] * wv.x;
        acc[i][1] += xr[i] * wv.y;
        acc[i][2] += xr[i] * wv.z;
        acc[i][3] += xr[i] * wv.w;
      }
    }
    __syncthreads();
  }

#pragma unroll
  for (int i = 0; i < 4; ++i) {
    int gr = row0 + rg + i;
    if (gr < NROWS) {
      float4 v = {acc[i][0], acc[i][1], acc[i][2], acc[i][3]};
      *(float4*)(h + (size_t)gr * C + cg) = v;
    }
  }
}

// ---------------------------------------------------------------------------
// CSR build: histogram -> 3-phase exclusive scan -> scatter
// ---------------------------------------------------------------------------
__global__ __launch_bounds__(256) void hist_kernel(const int* __restrict__ row,
                                                   int* __restrict__ deg) {
  int e = blockIdx.x * 256 + threadIdx.x;
  if (e < E) atomicAdd(&deg[row[e]], 1);
}

__device__ inline int wave_incl_scan(int v, int lane) {
#pragma unroll
  for (int off = 1; off < 64; off <<= 1) {
    int t = __shfl_up(v, off, 64);
    if (lane >= off) v += t;
  }
  return v;
}

// per-block exclusive scan of deg -> rs; block totals -> bsums
__global__ __launch_bounds__(256) void scan_phase1(const int* __restrict__ deg,
                                                   int* __restrict__ rs,
                                                   int* __restrict__ bsums) {
  int i = blockIdx.x * 256 + threadIdx.x;
  int lane = threadIdx.x & 63, wave = threadIdx.x >> 6;
  int d = (i < NROWS) ? deg[i] : 0;
  int inc = wave_incl_scan(d, lane);
  __shared__ int wtot[4];
  if (lane == 63) wtot[wave] = inc;
  __syncthreads();
  int woff = 0;
  for (int wv = 0; wv < wave; ++wv) woff += wtot[wv];
  if (i < NROWS) rs[i] = woff + inc - d;
  if (threadIdx.x == 255) bsums[blockIdx.x] = woff + inc;
}

// in-place exclusive scan of the block sums (nb <= 512), single block
__global__ __launch_bounds__(512) void scan_phase2(int* __restrict__ bsums, int nb) {
  int t = threadIdx.x, lane = t & 63, wave = t >> 6;
  int d = (t < nb) ? bsums[t] : 0;
  int inc = wave_incl_scan(d, lane);
  __shared__ int wtot[8];
  if (lane == 63) wtot[wave] = inc;
  __syncthreads();
  int woff = 0;
  for (int wv = 0; wv < wave; ++wv) woff += wtot[wv];
  if (t < nb) bsums[t] = woff + inc - d;
}

// add block offsets; init cursor; write sentinel
__global__ __launch_bounds__(256) void scan_phase3(int* __restrict__ rs,
                                                   const int* __restrict__ bsums,
                                                   int* __restrict__ cur) {
  int i = blockIdx.x * 256 + threadIdx.x;
  if (i < NROWS) {
    int v = rs[i] + bsums[blockIdx.x];
    rs[i]  = v;
    cur[i] = v;
  }
  if (i == 0) rs[NROWS] = E;
}

__global__ __launch_bounds__(256) void scatter_kernel(const int* __restrict__ row,
                                                      const int* __restrict__ col,
                                                      const float* __restrict__ val,
                                                      int* cur, int2* __restrict__ pack) {
  int e = blockIdx.x * 256 + threadIdx.x;
  if (e >= E) return;
  int r   = row[e];
  int pos = atomicAdd(&cur[r], 1);
  pack[pos] = make_int2(col[e], __float_as_int(val[e]));
}

// ---------------------------------------------------------------------------
// Pull-based SPMM: one wave per row, lane = column. No atomics.
// ---------------------------------------------------------------------------
__global__ __launch_bounds__(256) void spmm_pull(const int* __restrict__ rs,
                                                 const int2* __restrict__ pack,
                                                 const float* __restrict__ hin,
                                                 float* __restrict__ hout) {
  int r = blockIdx.x * 4 + (threadIdx.x >> 6);
  if (r >= NROWS) return;
  int lane  = threadIdx.x & 63;
  int start = rs[r], end = rs[r + 1];
  float acc = 0.f;
  for (int base = start; base < end; base += 64) {
    int idx = base + lane;
    int2 p  = (idx < end) ? pack[idx] : make_int2(0, 0);  // col 0 / val 0 pad is safe
    int n   = min(64, end - base);
    int nn  = (n + 3) & ~3;
    for (int j = 0; j < nn; j += 4) {
      // j is wave-uniform -> these lower to v_readlane broadcasts
      int   c0 = __shfl(p.x, j, 64),     c1 = __shfl(p.x, j + 1, 64);
      int   c2 = __shfl(p.x, j + 2, 64), c3 = __shfl(p.x, j + 3, 64);
      float v0 = __int_as_float(__shfl(p.y, j, 64));
      float v1 = __int_as_float(__shfl(p.y, j + 1, 64));
      float v2 = __int_as_float(__shfl(p.y, j + 2, 64));
      float v3 = __int_as_float(__shfl(p.y, j + 3, 64));
      float g0 = hin[(size_t)c0 * C + lane];
      float g1 = hin[(size_t)c1 * C + lane];
      float g2 = hin[(size_t)c2 * C + lane];
      float g3 = hin[(size_t)c3 * C + lane];
      acc += v0 * g0; acc += v1 * g1; acc += v2 * g2; acc += v3 * g3;
    }
  }
  hout[(size_t)r * C + lane] = acc;
}

// ---------------------------------------------------------------------------
// Fallback SPMM (atomic push) if ws too small for CSR
// ---------------------------------------------------------------------------
__global__ __launch_bounds__(256) void spmm_atomic(const int* __restrict__ row,
                                                   const int* __restrict__ col,
                                                   const float* __restrict__ val,
                                                   const float* __restrict__ hin,
                                                   float* hout) {
  int e = blockIdx.x * 4 + (threadIdx.x >> 6);
  if (e >= E) return;
  int   c  = threadIdx.x & 63;
  int   r  = row[e];
  int   cl = col[e];
  float v  = val[e];
  atomicAdd(&hout[(size_t)r * C + c], v * hin[(size_t)cl * C + c]);
}

// ---------------------------------------------------------------------------
// bias + log_softmax, one wave per row (C=64 = wave width)
// ---------------------------------------------------------------------------
__global__ __launch_bounds__(256) void bias_lsm(const float* __restrict__ h,
                                                const float* __restrict__ bias,
                                                float* __restrict__ out) {
  int r = blockIdx.x * 4 + (threadIdx.x >> 6);
  if (r >= NROWS) return;
  int   c = threadIdx.x & 63;
  float v = h[(size_t)r * C + c] + bias[c];

  float m = v;
#pragma unroll
  for (int off = 32; off; off >>= 1) m = fmaxf(m, __shfl_xor(m, off, 64));
  float ex = __expf(v - m);
  float s  = ex;
#pragma unroll
  for (int off = 32; off; off >>= 1) s += __shfl_xor(s, off, 64);

  out[(size_t)r * C + c] = v - m - __logf(s);
}

// ---------------------------------------------------------------------------
extern "C" void kernel_launch(void* const* d_in, const int* in_sizes, int n_in,
                              void* d_out, int out_size, void* d_ws, size_t ws_size,
                              hipStream_t stream) {
  const float* x    = (const float*)d_in[0];
  const float* w    = (const float*)d_in[1];
  const float* bias = (const float*)d_in[2];
  const int*   erow = (const int*)d_in[3];
  const int*   ecol = (const int*)d_in[4];
  const float* eval = (const float*)d_in[5];

  float* out = (float*)d_out;

  const size_t hbytes = (size_t)NROWS * C * sizeof(float);   // 25.6 MB
  char* ws = (char*)d_ws;
  float* h0 = (float*)ws;                       ws += hbytes;
  float* h1 = (float*)ws;                       ws += hbytes;

  const int nblk_rows  = (NROWS + 255) / 256;   // 391
  const int nblk_edges = (E + 255) / 256;       // 12500

  size_t need = 2 * hbytes + (size_t)E * 8 + 400016 + (size_t)NROWS * 4 + 4096;

  // h0 = x @ w
  gemm64<<<(NROWS + 63) / 64, 256, 0, stream>>>(x, w, h0);

  if (ws_size >= need) {
    int2* pack  = (int2*)ws;                    ws += (size_t)E * 8;
    int*  rs    = (int*)ws;                     ws += 400016;         // N+1 ints, padded
    int*  cur   = (int*)ws;                     ws += (size_t)NROWS * 4;
    int*  bsums = (int*)ws;

    // ---- build CSR ----
    hipMemsetAsync(cur, 0, (size_t)NROWS * 4, stream);
    hist_kernel<<<nblk_edges, 256, 0, stream>>>(erow, cur);
    scan_phase1<<<nblk_rows, 256, 0, stream>>>(cur, rs, bsums);
    scan_phase2<<<1, 512, 0, stream>>>(bsums, nblk_rows);
    scan_phase3<<<nblk_rows, 256, 0, stream>>>(rs, bsums, cur);
    scatter_kernel<<<nblk_edges, 256, 0, stream>>>(erow, ecol, eval, cur, pack);

    // ---- two propagation layers, pull-based ----
    spmm_pull<<<(NROWS + 3) / 4, 256, 0, stream>>>(rs, pack, h0, h1);
    spmm_pull<<<(NROWS + 3) / 4, 256, 0, stream>>>(rs, pack, h1, h0);
  } else {
    // fallback: atomic push
    hipMemsetAsync(h1, 0, hbytes, stream);
    spmm_atomic<<<(E + 3) / 4, 256, 0, stream>>>(erow, ecol, eval, h0, h1);
    hipMemsetAsync(h0, 0, hbytes, stream);
    spmm_atomic<<<(E + 3) / 4, 256, 0, stream>>>(erow, ecol, eval, h1, h0);
  }

  // out = log_softmax(h0 + bias)
  bias_lsm<<<(NROWS + 3) / 4, 256, 0, stream>>>(h0, bias, out);
}

// Round 3
// 953.748 us; speedup vs baseline: 1.8406x; 1.0050x over previous
//
#include <hip/hip_runtime.h>
#include <hip/hip_bf16.h>

// Problem constants (fixed by setup_inputs)
constexpr int NROWS = 100000;
constexpr int K     = 512;
constexpr int C     = 64;
constexpr int E     = 3200000;
constexpr int SH    = 8;                 // cursor shards (XCD-locality heuristic)
constexpr int M8    = NROWS * SH;        // sharded counter space

// ---------------------------------------------------------------------------
// GEMM: h[N,64] = x[N,512] @ w[512,64], fp32 vector ALU.
// Tile 128 rows x 64 cols, KC=64, 8x4 register blocking per thread.
// Per kk: 8 ds_read_b32 (broadcast) + 1 ds_read_b128 per 32 FMAs -> VALU-bound.
// ---------------------------------------------------------------------------
__global__ __launch_bounds__(256) void gemm64(const float* __restrict__ x,
                                              const float* __restrict__ w,
                                              float* __restrict__ h) {
  __shared__ float xs[128][65];   // +1 pad: broadcast reads conflict-free
  __shared__ float ws[64][64];
  const int t    = threadIdx.x;
  const int cg   = (t & 15) * 4;   // col base: 0..60
  const int rg   = (t >> 4) * 8;   // row base: 0..120
  const int row0 = blockIdx.x * 128;

  float acc[8][4] = {};

  for (int k0 = 0; k0 < K; k0 += 64) {
    // stage W chunk [64k x 64c] = 1024 float4, 4 per thread (coalesced)
    {
      const float4* wg  = (const float4*)(w + (size_t)k0 * C);
      float4*       wsv = (float4*)&ws[0][0];
#pragma unroll
      for (int i = 0; i < 4; ++i) wsv[t + 256 * i] = wg[t + 256 * i];
    }
    // stage x chunk [128r x 64k] = 2048 float4, 8 per thread (coalesced)
#pragma unroll
    for (int i = 0; i < 8; ++i) {
      int idx = t + 256 * i;          // 0..2047
      int r   = idx >> 4;             // 0..127
      int kk  = (idx & 15) * 4;       // 0..60
      int gr  = row0 + r;
      if (gr >= NROWS) gr = NROWS - 1;   // clamp: OOB-safe, result discarded
      float4 v = *(const float4*)(x + (size_t)gr * K + k0 + kk);
      xs[r][kk]     = v.x;
      xs[r][kk + 1] = v.y;
      xs[r][kk + 2] = v.z;
      xs[r][kk + 3] = v.w;
    }
    __syncthreads();

#pragma unroll 8
    for (int kk = 0; kk < 64; ++kk) {
      float4 wv = *(const float4*)&ws[kk][cg];
      float xr[8];
#pragma unroll
      for (int i = 0; i < 8; ++i) xr[i] = xs[rg + i][kk];
#pragma unroll
      for (int i = 0; i < 8; ++i) {
        acc[i][0] += xr[i] * wv.x;
        acc[i][1] += xr[i] * wv.y;
        acc[i][2] += xr[i] * wv.z;
        acc[i][3] += xr[i] * wv.w;
      }
    }
    __syncthreads();
  }

#pragma unroll
  for (int i = 0; i < 8; ++i) {
    int gr = row0 + rg + i;
    if (gr < NROWS) {
      float4 v = {acc[i][0], acc[i][1], acc[i][2], acc[i][3]};
      *(float4*)(h + (size_t)gr * C + cg) = v;
    }
  }
}

// ---------------------------------------------------------------------------
// CSR build (8-sharded): histogram -> 3-phase exclusive scan -> scatter.
// Counter index = row*8 + (blockIdx&7). With round-robin blockIdx->XCD
// mapping, each cursor is written by one XCD => pack lines fill completely
// in that XCD's L2 before writeback (full 64B lines instead of 8B-dirty).
// Row r's edges remain contiguous: [rs[8r], rs[8r+8]).
// ---------------------------------------------------------------------------
__global__ __launch_bounds__(256) void hist_kernel(const int* __restrict__ row,
                                                   int* __restrict__ deg) {
  int e = blockIdx.x * 256 + threadIdx.x;
  if (e < E) atomicAdd(&deg[row[e] * SH + (blockIdx.x & (SH - 1))], 1);
}

__device__ inline int wave_incl_scan(int v, int lane) {
#pragma unroll
  for (int off = 1; off < 64; off <<= 1) {
    int t = __shfl_up(v, off, 64);
    if (lane >= off) v += t;
  }
  return v;
}

// per-block (1024 elems) exclusive scan of deg -> rs; block totals -> bsums
__global__ __launch_bounds__(1024) void scan_phase1(const int* __restrict__ deg,
                                                    int* __restrict__ rs,
                                                    int* __restrict__ bsums) {
  int i = blockIdx.x * 1024 + threadIdx.x;
  int lane = threadIdx.x & 63, wave = threadIdx.x >> 6;   // wave 0..15
  int d = (i < M8) ? deg[i] : 0;
  int inc = wave_incl_scan(d, lane);
  __shared__ int wtot[16];
  if (lane == 63) wtot[wave] = inc;
  __syncthreads();
  int woff = 0;
  for (int wv = 0; wv < wave; ++wv) woff += wtot[wv];
  if (i < M8) rs[i] = woff + inc - d;
  if (threadIdx.x == 1023) bsums[blockIdx.x] = woff + inc;
}

// in-place exclusive scan of block sums (nb <= 1024), single block
__global__ __launch_bounds__(1024) void scan_phase2(int* __restrict__ bsums, int nb) {
  int t = threadIdx.x, lane = t & 63, wave = t >> 6;
  int d = (t < nb) ? bsums[t] : 0;
  int inc = wave_incl_scan(d, lane);
  __shared__ int wtot[16];
  if (lane == 63) wtot[wave] = inc;
  __syncthreads();
  int woff = 0;
  for (int wv = 0; wv < wave; ++wv) woff += wtot[wv];
  if (t < nb) bsums[t] = woff + inc - d;
}

// add block offsets; init cursors; write sentinel
__global__ __launch_bounds__(256) void scan_phase3(int* __restrict__ rs,
                                                   const int* __restrict__ bsums,
                                                   int* __restrict__ cur) {
  int i = blockIdx.x * 256 + threadIdx.x;
  if (i < M8) {
    int v = rs[i] + bsums[i >> 10];
    rs[i]  = v;
    cur[i] = v;
  }
  if (i == 0) rs[M8] = E;
}

__global__ __launch_bounds__(256) void scatter_kernel(const int* __restrict__ row,
                                                      const int* __restrict__ col,
                                                      const float* __restrict__ val,
                                                      int* cur, int2* __restrict__ pack) {
  int e = blockIdx.x * 256 + threadIdx.x;
  if (e >= E) return;
  int r   = row[e];
  int pos = atomicAdd(&cur[r * SH + (blockIdx.x & (SH - 1))], 1);
  pack[pos] = make_int2(col[e], __float_as_int(val[e]));
}

// ---------------------------------------------------------------------------
// Pull-based SPMM: one wave per row, lane = column. No atomics.
// ---------------------------------------------------------------------------
__global__ __launch_bounds__(256) void spmm_pull(const int* __restrict__ rs,
                                                 const int2* __restrict__ pack,
                                                 const float* __restrict__ hin,
                                                 float* __restrict__ hout) {
  int r = blockIdx.x * 4 + (threadIdx.x >> 6);
  if (r >= NROWS) return;
  int lane  = threadIdx.x & 63;
  int start = rs[r * SH], end = rs[r * SH + SH];
  float acc = 0.f;
  for (int base = start; base < end; base += 64) {
    int idx = base + lane;
    int2 p  = (idx < end) ? pack[idx] : make_int2(0, 0);  // col 0 / val 0 pad is safe
    int n   = min(64, end - base);
    int nn  = (n + 3) & ~3;
    for (int j = 0; j < nn; j += 4) {
      // j is wave-uniform -> these lower to v_readlane broadcasts
      int   c0 = __shfl(p.x, j, 64),     c1 = __shfl(p.x, j + 1, 64);
      int   c2 = __shfl(p.x, j + 2, 64), c3 = __shfl(p.x, j + 3, 64);
      float v0 = __int_as_float(__shfl(p.y, j, 64));
      float v1 = __int_as_float(__shfl(p.y, j + 1, 64));
      float v2 = __int_as_float(__shfl(p.y, j + 2, 64));
      float v3 = __int_as_float(__shfl(p.y, j + 3, 64));
      float g0 = hin[(size_t)c0 * C + lane];
      float g1 = hin[(size_t)c1 * C + lane];
      float g2 = hin[(size_t)c2 * C + lane];
      float g3 = hin[(size_t)c3 * C + lane];
      acc += v0 * g0; acc += v1 * g1; acc += v2 * g2; acc += v3 * g3;
    }
  }
  hout[(size_t)r * C + lane] = acc;
}

// ---------------------------------------------------------------------------
// Fallback SPMM (atomic push) if ws too small for CSR
// ---------------------------------------------------------------------------
__global__ __launch_bounds__(256) void spmm_atomic(const int* __restrict__ row,
                                                   const int* __restrict__ col,
                                                   const float* __restrict__ val,
                                                   const float* __restrict__ hin,
                                                   float* hout) {
  int e = blockIdx.x * 4 + (threadIdx.x >> 6);
  if (e >= E) return;
  int   c  = threadIdx.x & 63;
  int   r  = row[e];
  int   cl = col[e];
  float v  = val[e];
  atomicAdd(&hout[(size_t)r * C + c], v * hin[(size_t)cl * C + c]);
}

// ---------------------------------------------------------------------------
// bias + log_softmax, one wave per row (C=64 = wave width)
// ---------------------------------------------------------------------------
__global__ __launch_bounds__(256) void bias_lsm(const float* __restrict__ h,
                                                const float* __restrict__ bias,
                                                float* __restrict__ out) {
  int r = blockIdx.x * 4 + (threadIdx.x >> 6);
  if (r >= NROWS) return;
  int   c = threadIdx.x & 63;
  float v = h[(size_t)r * C + c] + bias[c];

  float m = v;
#pragma unroll
  for (int off = 32; off; off >>= 1) m = fmaxf(m, __shfl_xor(m, off, 64));
  float ex = __expf(v - m);
  float s  = ex;
#pragma unroll
  for (int off = 32; off; off >>= 1) s += __shfl_xor(s, off, 64);

  out[(size_t)r * C + c] = v - m - __logf(s);
}

// ---------------------------------------------------------------------------
extern "C" void kernel_launch(void* const* d_in, const int* in_sizes, int n_in,
                              void* d_out, int out_size, void* d_ws, size_t ws_size,
                              hipStream_t stream) {
  const float* x    = (const float*)d_in[0];
  const float* w    = (const float*)d_in[1];
  const float* bias = (const float*)d_in[2];
  const int*   erow = (const int*)d_in[3];
  const int*   ecol = (const int*)d_in[4];
  const float* eval = (const float*)d_in[5];

  float* out = (float*)d_out;

  const size_t hbytes = (size_t)NROWS * C * sizeof(float);   // 25.6 MB
  char* ws = (char*)d_ws;
  float* h0 = (float*)ws;                       ws += hbytes;
  float* hA = out;   // d_out doubles as intermediate h buffer (same size/type)

  const int nblk_edges = (E + 255) / 256;       // 12500
  const int nb1        = (M8 + 1023) / 1024;    // 782 scan blocks

  size_t need = hbytes + (size_t)E * 8 + ((size_t)M8 + 16) * 4 + (size_t)M8 * 4 + 8192;

  // h0 = x @ w
  gemm64<<<(NROWS + 127) / 128, 256, 0, stream>>>(x, w, h0);

  if (ws_size >= need) {
    int2* pack  = (int2*)ws;                    ws += (size_t)E * 8;
    int*  rs    = (int*)ws;                     ws += ((size_t)M8 + 16) * 4;  // M8+1 ints, padded
    int*  cur   = (int*)ws;                     ws += (size_t)M8 * 4;         // also deg
    int*  bsums = (int*)ws;

    // ---- build sharded CSR ----
    hipMemsetAsync(cur, 0, (size_t)M8 * 4, stream);
    hist_kernel<<<nblk_edges, 256, 0, stream>>>(erow, cur);          // cur = deg
    scan_phase1<<<nb1, 1024, 0, stream>>>(cur, rs, bsums);
    scan_phase2<<<1, 1024, 0, stream>>>(bsums, nb1);
    scan_phase3<<<(M8 + 255) / 256, 256, 0, stream>>>(rs, bsums, cur);
    scatter_kernel<<<nblk_edges, 256, 0, stream>>>(erow, ecol, eval, cur, pack);

    // ---- two propagation layers, pull-based ----
    spmm_pull<<<(NROWS + 3) / 4, 256, 0, stream>>>(rs, pack, h0, hA);
    spmm_pull<<<(NROWS + 3) / 4, 256, 0, stream>>>(rs, pack, hA, h0);
  } else {
    // fallback: atomic push (hA = d_out as scratch)
    hipMemsetAsync(hA, 0, hbytes, stream);
    spmm_atomic<<<(E + 3) / 4, 256, 0, stream>>>(erow, ecol, eval, h0, hA);
    hipMemsetAsync(h0, 0, hbytes, stream);
    spmm_atomic<<<(E + 3) / 4, 256, 0, stream>>>(erow, ecol, eval, hA, h0);
  }

  // out = log_softmax(h0 + bias)
  bias_lsm<<<(NROWS + 3) / 4, 256, 0, stream>>>(h0, bias, out);
}